// Round 1
// baseline (388.019 us; speedup 1.0000x reference)
//
#include <hip/hip_runtime.h>

#define B_   64
#define S_   2048
#define TRG_ 512
#define K_   1024

typedef short short8 __attribute__((ext_vector_type(8)));
typedef float f32x4  __attribute__((ext_vector_type(4)));
typedef unsigned short us4 __attribute__((ext_vector_type(4)));

__device__ __forceinline__ unsigned short f2bf(float f) {
    union { float f; unsigned int u; } v; v.f = f;
    unsigned int u = v.u;
    unsigned int r = (u + 0x7fffu + ((u >> 16) & 1u)) >> 16;  // RNE
    return (unsigned short)r;
}

// ---------------- W_en fp32 -> bf16 ----------------
__global__ void wen_convert_kernel(const float* __restrict__ Wen,
                                   unsigned short* __restrict__ Wbf) {
    int idx = blockIdx.x * 256 + threadIdx.x;          // 131072 float4s
    float4 f = ((const float4*)Wen)[idx];
    us4 o = { f2bf(f.x), f2bf(f.y), f2bf(f.z), f2bf(f.w) };
    ((us4*)Wbf)[idx] = o;
}

// ---------------- deproj[b,h] = b_en[h] + sum_t dehy[b,t]*W_de[h,t] ----------------
__global__ void deproj_kernel(const float* __restrict__ dehy,
                              const float* __restrict__ Wde,
                              const float* __restrict__ ben,
                              float* __restrict__ dp) {
    int b = blockIdx.x >> 1;
    int h = ((blockIdx.x & 1) << 8) + threadIdx.x;
    const float4* dv = (const float4*)(dehy + (size_t)b * TRG_);
    const float4* wv = (const float4*)(Wde + (size_t)h * TRG_);
    float s = ben[h];
    #pragma unroll 4
    for (int t = 0; t < TRG_ / 4; ++t) {
        float4 a = dv[t], w = wv[t];
        s += a.x * w.x + a.y * w.y + a.z * w.z + a.w * w.w;
    }
    dp[b * TRG_ + h] = s;
}

// ---------------- fused score GEMM + tanh + w_warp reduce + mask ----------------
// C[m,h] = sum_k enhy[m,k]*W_en[h,k]; tile 128(M) x 512(N=all h) x 32(K)
// 512 threads = 8 waves, wave grid 2(M) x 4(N); wave tile 64x128 -> 4x8 mfma frags
__global__ __launch_bounds__(512, 2) void score_kernel(
    const float* __restrict__ enhy,
    const unsigned short* __restrict__ Wbf,
    const float* __restrict__ dp,
    const float* __restrict__ past_attn,
    const int* __restrict__ src_mask,
    const float* __restrict__ w_cv,
    const float* __restrict__ w_warp,
    float* __restrict__ out_ee)
{
    __shared__ unsigned short Abuf[2][128 * 32];   // 16 KB
    __shared__ unsigned short Bbuf[2][512 * 32];   // 64 KB
    __shared__ float red[4][128];                  // 2 KB

    const int tid  = threadIdx.x;
    const int lane = tid & 63;
    const int w    = tid >> 6;
    const int wm   = w >> 2;          // 0..1
    const int wn   = w & 3;           // 0..3
    const int lj   = lane & 15;
    const int lg   = lane >> 4;
    const int m0   = blockIdx.x * 128;
    const int b    = m0 >> 11;
    const int s0   = m0 & 2047;

    // swizzled 16B-chunk offset for fragment reads: chunk = kgrp ^ (row&3); row&3 == lane&3
    const int kx = ((lg ^ (lane & 3)) << 4);

    f32x4 acc[4][8];
    const f32x4 fz = {0.f, 0.f, 0.f, 0.f};
    #pragma unroll
    for (int i = 0; i < 4; ++i)
        #pragma unroll
        for (int j = 0; j < 8; ++j) acc[i][j] = fz;

    // A staging: thread -> (row = tid>>2, 16B chunk = tid&3), 8 fp32 -> 8 bf16
    const int arow = tid >> 2;
    const int achk = tid & 3;
    const float* aSrc = enhy + (size_t)(m0 + arow) * K_ + (achk << 3);
    const int aDstByte = arow * 64 + ((achk ^ (arow & 3)) << 4);

    // B staging: 4 global_load_lds issues; source address pre-swizzled
    const unsigned short* bSrc[4];
    unsigned short* bDst[4];
    #pragma unroll
    for (int j = 0; j < 4; ++j) {
        int cp = (j << 9) + tid;           // chunk position 0..2047
        int brow = cp >> 2, bkc = cp & 3;
        bSrc[j] = Wbf + (size_t)brow * K_ + ((bkc ^ (brow & 3)) << 3);
        bDst[j] = &Bbuf[0][0] + ((j << 9) + (w << 6)) * 8;   // wave-uniform, 8 ushort = 16B units
    }

    float4 a0, a1;
    auto load_a = [&](int kt) {
        const float* p = aSrc + kt * 32;
        a0 = *(const float4*)p;
        a1 = *(const float4*)(p + 4);
    };
    auto write_a = [&](int bufsel) {
        short8 v;
        v[0] = (short)f2bf(a0.x); v[1] = (short)f2bf(a0.y);
        v[2] = (short)f2bf(a0.z); v[3] = (short)f2bf(a0.w);
        v[4] = (short)f2bf(a1.x); v[5] = (short)f2bf(a1.y);
        v[6] = (short)f2bf(a1.z); v[7] = (short)f2bf(a1.w);
        *(short8*)((char*)&Abuf[bufsel][0] + aDstByte) = v;
    };
    auto stage_b = [&](int bufsel, int kt) {
        #pragma unroll
        for (int j = 0; j < 4; ++j) {
            __builtin_amdgcn_global_load_lds(
                (const __attribute__((address_space(1))) void*)(bSrc[j] + kt * 32),
                (__attribute__((address_space(3))) void*)(bDst[j] + bufsel * (512 * 32)),
                16, 0, 0);
        }
    };
    auto compute = [&](int bufsel) {
        const char* Bbase = (const char*)&Bbuf[bufsel][0];
        const char* Abase = (const char*)&Abuf[bufsel][0];
        short8 bf[8];
        #pragma unroll
        for (int fn = 0; fn < 8; ++fn) {
            int r = (wn << 7) + (fn << 4) + lj;
            bf[fn] = *(const short8*)(Bbase + r * 64 + kx);
        }
        #pragma unroll
        for (int fm = 0; fm < 4; ++fm) {
            int rA = (wm << 6) + (fm << 4) + lj;
            short8 af = *(const short8*)(Abase + rA * 64 + kx);
            #pragma unroll
            for (int fn = 0; fn < 8; ++fn)
                acc[fm][fn] = __builtin_amdgcn_mfma_f32_16x16x32_bf16(af, bf[fn], acc[fm][fn], 0, 0, 0);
        }
    };

    // prologue
    load_a(0);
    stage_b(0, 0);
    write_a(0);
    __syncthreads();

    int buf = 0;
    for (int kt = 0; kt < 32; ++kt) {
        if (kt < 31) {
            load_a(kt + 1);            // issue early (latency hides under MFMA)
            stage_b(buf ^ 1, kt + 1);
        }
        compute(buf);
        if (kt < 31) write_a(buf ^ 1); // cvt+ds_write late (T14 split)
        __syncthreads();
        buf ^= 1;
    }

    // ---- epilogue: v=acc+dep+pa*wcv; tanh; *w_warp; reduce over all 512 h ----
    float dep[8], wcv8[8], wwp8[8];
    #pragma unroll
    for (int fn = 0; fn < 8; ++fn) {
        int h = (wn << 7) + (fn << 4) + lj;
        dep[fn]  = dp[b * TRG_ + h];
        wcv8[fn] = w_cv[h];
        wwp8[fn] = w_warp[h];
    }
    #pragma unroll
    for (int fm = 0; fm < 4; ++fm) {
        #pragma unroll
        for (int reg = 0; reg < 4; ++reg) {
            int rloc = (wm << 6) + (fm << 4) + (lg << 2) + reg;
            float pa = past_attn[b * S_ + s0 + rloc];
            float p = 0.f;
            #pragma unroll
            for (int fn = 0; fn < 8; ++fn) {
                float v = acc[fm][fn][reg] + dep[fn] + pa * wcv8[fn];
                float e = __expf(2.f * v);                       // tanh = 1 - 2/(e^{2v}+1)
                float t = 1.f - 2.f * __builtin_amdgcn_rcpf(e + 1.f);
                p += t * wwp8[fn];
            }
            p += __shfl_xor(p, 1);
            p += __shfl_xor(p, 2);
            p += __shfl_xor(p, 4);
            p += __shfl_xor(p, 8);
            if (lj == 0) red[wn][rloc] = p;
        }
    }
    __syncthreads();
    if (tid < 128) {
        float ee = red[0][tid] + red[1][tid] + red[2][tid] + red[3][tid];
        int msk = src_mask[b * S_ + s0 + tid];
        if (msk == 0) ee = -1e20f;
        out_ee[m0 + tid] = ee;
    }
}

// ---------------- softmax over S per batch row ----------------
__global__ void softmax_kernel(const float* __restrict__ ee, float* __restrict__ attn) {
    int b = blockIdx.x, tid = threadIdx.x;   // 256 threads
    const float* row = ee + (size_t)b * S_;
    float v[8]; float mx = -3.0e38f;
    #pragma unroll
    for (int i = 0; i < 8; ++i) { v[i] = row[tid + (i << 8)]; mx = fmaxf(mx, v[i]); }
    #pragma unroll
    for (int off = 32; off > 0; off >>= 1) mx = fmaxf(mx, __shfl_xor(mx, off));
    __shared__ float sred[4];
    int w = tid >> 6, lane = tid & 63;
    if (lane == 0) sred[w] = mx;
    __syncthreads();
    mx = fmaxf(fmaxf(sred[0], sred[1]), fmaxf(sred[2], sred[3]));
    float sum = 0.f;
    #pragma unroll
    for (int i = 0; i < 8; ++i) { v[i] = __expf(v[i] - mx); sum += v[i]; }
    #pragma unroll
    for (int off = 32; off > 0; off >>= 1) sum += __shfl_xor(sum, off);
    __syncthreads();
    if (lane == 0) sred[w] = sum;
    __syncthreads();
    sum = sred[0] + sred[1] + sred[2] + sred[3];
    float inv = 1.f / sum;
    float* orow = attn + (size_t)b * S_;
    #pragma unroll
    for (int i = 0; i < 8; ++i) orow[tid + (i << 8)] = v[i] * inv;
}

// ---------------- context: partial over s-chunks (deterministic) ----------------
__global__ void ctx_partial_kernel(const float* __restrict__ attn,
                                   const float* __restrict__ enhy,
                                   float* __restrict__ part) {
    int bx = blockIdx.x;              // 64*32
    int b = bx >> 5, sc = bx & 31;
    int tid = threadIdx.x;            // 256; each thread one float4 of d
    const float4* e4 = (const float4*)(enhy + ((size_t)b * S_ + sc * 64) * K_);
    const float* ar = attn + (size_t)b * S_ + sc * 64;
    float4 acc = {0.f, 0.f, 0.f, 0.f};
    #pragma unroll 4
    for (int s = 0; s < 64; ++s) {
        float a = ar[s];
        float4 ev = e4[(size_t)s * 256 + tid];
        acc.x += a * ev.x; acc.y += a * ev.y; acc.z += a * ev.z; acc.w += a * ev.w;
    }
    ((float4*)part)[(size_t)(sc * 64 + b) * 256 + tid] = acc;
}

__global__ void ctx_reduce_kernel(const float* __restrict__ part, float* __restrict__ outc) {
    int idx = blockIdx.x * 256 + threadIdx.x;   // 65536
    int b = idx >> 10, d = idx & 1023;
    float s = 0.f;
    #pragma unroll
    for (int sc = 0; sc < 32; ++sc) s += part[(size_t)((sc << 6) + b) * 1024 + d];
    outc[idx] = s;
}

extern "C" void kernel_launch(void* const* d_in, const int* in_sizes, int n_in,
                              void* d_out, int out_size, void* d_ws, size_t ws_size,
                              hipStream_t stream) {
    (void)in_sizes; (void)n_in; (void)out_size; (void)ws_size;

    const float* dehy = (const float*)d_in[0];
    const float* enhy = (const float*)d_in[1];
    const float* past = (const float*)d_in[2];
    const int*   mask = (const int*)d_in[3];
    const float* Wen  = (const float*)d_in[4];
    const float* ben  = (const float*)d_in[5];
    const float* Wde  = (const float*)d_in[6];
    const float* wcv  = (const float*)d_in[7];
    const float* wwp  = (const float*)d_in[8];

    float* out      = (float*)d_out;
    float* out_c    = out;                      // 64*1024
    float* out_attn = out + 65536;              // 64*2048
    float* out_ee   = out + 65536 + 131072;     // 64*2048

    char* ws = (char*)d_ws;
    unsigned short* Wbf = (unsigned short*)ws;              // 1 MB
    float* dp   = (float*)(ws + (1 << 20));                 // 128 KB
    float* part = (float*)(ws + (1 << 20) + (1 << 17));     // 8 MB

    wen_convert_kernel<<<512, 256, 0, stream>>>(Wen, Wbf);
    deproj_kernel<<<128, 256, 0, stream>>>(dehy, Wde, ben, dp);
    score_kernel<<<1024, 512, 0, stream>>>(enhy, Wbf, dp, past, mask, wcv, wwp, out_ee);
    softmax_kernel<<<64, 256, 0, stream>>>(out_ee, out_attn);
    ctx_partial_kernel<<<2048, 256, 0, stream>>>(out_attn, enhy, part);
    ctx_reduce_kernel<<<256, 256, 0, stream>>>(part, out_c);
}